// Round 8
// baseline (452.315 us; speedup 1.0000x reference)
//
#include <hip/hip_runtime.h>
#include <cmath>
#include <cstdint>
#include <cstddef>

typedef _Float16 f16;
typedef _Float16 f16x2 __attribute__((ext_vector_type(2)));
typedef _Float16 f16x8 __attribute__((ext_vector_type(8)));
typedef float f32x4 __attribute__((ext_vector_type(4)));

// ---- problem constants ----
#define BATCH 8
#define CIN   512
#define COUT  512
#define S0    64      // input spatial
#define S1    66      // conv output spatial (pad 2, k=3)
#define PADH  68      // padded input spatial for conv
#define P_TOT (S1*S1) // 4356 spatial positions per image
#define MID   138     // mid (upsampled+filtered) spatial
#define OUTS  64      // final output spatial

struct FirParams { float fu[12]; float fd[12]; };

// ---------------------------------------------------------------- helpers
__device__ __forceinline__ void async16(const char* g, char* l) {
  __builtin_amdgcn_global_load_lds((const __attribute__((address_space(1))) void*)g,
                                   (__attribute__((address_space(3))) void*)l, 16, 0, 0);
}

// ---------------------------------------------------------------- K1: fused k_wg + k_styles (independent preps, one launch)
// blocks 0..511: wg role (weight repack + per-O sumsq g)
// blocks 512..1535: styles role (w @ aw^T + ab, global sumsq atomic)
__global__ __launch_bounds__(256) void k_prep(const float* __restrict__ cw,
                                              f16* __restrict__ Wp,
                                              float* __restrict__ g,
                                              const float* __restrict__ w,
                                              const float* __restrict__ aw,
                                              const float* __restrict__ ab,
                                              float* __restrict__ styles,
                                              float* __restrict__ sumsq) {
  __shared__ float part[4];
  if (blockIdx.x < 512) {            // ---- wg role ----
    int O = blockIdx.x;
    const float* base = cw + (size_t)O*4608;
    for (int I = threadIdx.x; I < 512; I += 256) {
      float v[9]; float s = 0.f;
      #pragma unroll
      for (int t = 0; t < 9; ++t) { v[t] = base[I*9 + t]; s += v[t]*v[t]; }
      g[(size_t)O*512 + I] = s;
      #pragma unroll
      for (int t = 0; t < 9; ++t) Wp[((size_t)O*9 + t)*512 + I] = (f16)v[t];
    }
    return;
  }
  // ---- styles role ----
  int wave = threadIdx.x >> 6, lane = threadIdx.x & 63;
  int gid = (blockIdx.x - 512)*4 + wave;         // 0..4095
  int b = gid >> 9, i = gid & 511;
  const float* wr = w + b*512;
  const float* ar = aw + (size_t)i*512;
  float acc = 0.f;
  #pragma unroll
  for (int k = 0; k < 8; ++k) acc += wr[lane + 64*k]*ar[lane + 64*k];
  for (int off = 32; off; off >>= 1) acc += __shfl_down(acc, off);
  if (lane == 0) {
    float v = acc*0.044194173824159216f + ab[i];  // 1/sqrt(512)
    styles[gid] = v;
    part[wave] = v*v;
  }
  __syncthreads();
  if (threadIdx.x == 0) atomicAdd(sumsq, part[0]+part[1]+part[2]+part[3]);
}

// ---------------------------------------------------------------- K4: fused k_xmod + k_halo + k_scale (one launch)
// blocks < 2048:        Xm[b][ih+2][iw+2][I] = f16(x*styles*scale), interior.
//                       float4 reads (16B/lane) + f16x8 stores (16B/lane).
// blocks 2048..3103:    zero Xm halo strips.
// blocks 3104..4127:    scale role (was k_scale): one (b,O) per wave,
//                       pure shfl reduce — math identical to k_scale.
__global__ __launch_bounds__(256) void k_xm(const float* __restrict__ x,
                                            const float* __restrict__ styles,
                                            const float* __restrict__ sumsq,
                                            f16* __restrict__ Xm,
                                            const float* __restrict__ g,
                                            float* __restrict__ sco) {
  __shared__ float tile[128][65];
  if (blockIdx.x >= 3104) {          // ---- scale role ----
    int wave = threadIdx.x >> 6, lane = threadIdx.x & 63;
    int blk2 = (blockIdx.x - 3104)*4 + wave;      // 0..4095 = b*512 + O
    int b = blk2 >> 9, O = blk2 & 511;
    const float* gr = g + (size_t)O*512;
    const float* sr = styles + b*512;
    float a1 = 0.f, a2 = 0.f;
    for (int I = lane; I < 512; I += 64) {
      float gg = gr[I], ss = sr[I];
      a1 += gg*ss*ss; a2 += gg;
    }
    for (int off = 32; off; off >>= 1) {
      a1 += __shfl_down(a1, off);
      a2 += __shfl_down(a2, off);
    }
    if (lane == 0) {
      float kf = 4096.0f / (*sumsq);              // rsqrt(mean styles^2)^2
      a1 *= kf;
      float wn2 = 4608.f / a2;                    // 1/mean(wgt^2)
      sco[blk2] = sqrtf(wn2) / sqrtf(wn2*a1 + 1e-8f);
    }
    return;
  }
  if (blockIdx.x >= 2048) {          // ---- halo role ----
    int pix = (blockIdx.x - 2048)*4 + (threadIdx.x >> 6);   // 0..4223
    int lane = threadIdx.x & 63;
    int img = pix / 528, t = pix - img*528;
    int row, col;
    if (t < 272) { int rid = t/68; col = t - rid*68; row = (rid < 2) ? rid : 64 + rid; }
    else { int t2 = t - 272; int rid = t2 >> 2, cid = t2 & 3; row = rid + 2; col = (cid < 2) ? cid : 64 + cid; }
    float4* p = (float4*)(Xm + ((size_t)(img*PADH + row)*PADH + col)*512);
    p[lane] = make_float4(0.f, 0.f, 0.f, 0.f);
    return;
  }
  int blk = blockIdx.x;              // b*256 + ih*4 + ic
  int ic = blk & 3, ih = (blk >> 2) & 63, b = blk >> 8;
  int I0 = ic*128;
  float sc = sqrtf(4096.0f / (*sumsq));
  const float* xp = x + (((size_t)b*512 + I0)*64 + ih)*64;
  for (int idx = threadIdx.x; idx < 128*16; idx += 256) {
    int Il = idx >> 4, iw4 = (idx & 15) << 2;
    float4 v = *(const float4*)&xp[(size_t)Il*4096 + iw4];
    float s = styles[b*512 + I0 + Il]*sc;
    tile[Il][iw4+0] = v.x*s;
    tile[Il][iw4+1] = v.y*s;
    tile[Il][iw4+2] = v.z*s;
    tile[Il][iw4+3] = v.w*s;
  }
  __syncthreads();
  f16* op = Xm + (((size_t)b*PADH + ih + 2)*PADH + 2)*512 + I0;
  for (int idx = threadIdx.x; idx < 64*16; idx += 256) {
    int iw = idx >> 4, Il0 = (idx & 15) << 3;
    f16x8 vv;
    #pragma unroll
    for (int k = 0; k < 8; ++k) vv[k] = (f16)tile[Il0 + k][iw];
    *(f16x8*)(op + (size_t)iw*512 + Il0) = vv;
  }
}

// ---------------------------------------------------------------- K6: modulated conv as 9-tap implicit GEMM
// 128 O x 128 p tiles, grid 1120 (4.4 blocks/CU for latency hiding).
// b = gid&7 pins image to XCD; within XCD pt fastest + boustrophedon for L2.
// 35 pt-tiles; last overlaps (4228..4355) -> guard-free duplicate stores.
// (v1 reverted: explicit dbuf cut occupancy 5->2 blocks/CU, -25% — cross-block
//  wave overlap at 32KB LDS IS the pipeline; keep 2-barrier structure.)
// At 880 TF this sits at the m97-structure ceiling.
__global__ __launch_bounds__(256) void k_conv(const f16* __restrict__ Wp,
                                              const f16* __restrict__ Xm,
                                              const float* __restrict__ sco,
                                              const float* __restrict__ bias,
                                              f16* __restrict__ y1) {
  __shared__ f16x8 As[1024];   // 128 rows x 128B (16KB)
  __shared__ f16x8 Bs[1024];
  const int tid = threadIdx.x, lane = tid & 63, wave = tid >> 6;
  const int gid = blockIdx.x;
  const int b = gid & 7;
  const int r = gid >> 3;            // 0..139
  const int Oi = r / 35;
  int pi = r - Oi*35;                // 0..34
  if (Oi & 1) pi = 34 - pi;          // boustrophedon
  const int Ot = Oi * 128;
  const int pt0 = (pi < 34) ? pi*128 : 4228;

  const int srow = wave*32 + (lane >> 3);
  const int cglob = (lane & 7) ^ (lane >> 3);     // global chunk feeding physical chunk lane&7
  const char* aP[4]; const char* bP[4];
  #pragma unroll
  for (int q = 0; q < 4; ++q) {
    aP[q] = (const char*)Wp + (size_t)(Ot + srow + q*8)*9216 + cglob*16;
    int p = pt0 + srow + q*8;                      // always <= 4355
    int oh = p/66, ow = p - oh*66;
    bP[q] = (const char*)Xm + (((size_t)b*PADH + oh)*PADH + ow)*1024 + cglob*16;
  }
  char* aL = (char*)As + wave*32*128;
  char* bL = (char*)Bs + wave*32*128;

  f32x4 acc[4][4] = {};
  const int wO = (wave & 1)*64, wPq = (wave >> 1)*64;
  const int m = lane & 15, quad = lane >> 4, mx = m & 7;

  for (int tap = 0; tap < 9; ++tap) {
    const int kh = tap/3, kw = tap - kh*3;
    const uint32_t bTap = (uint32_t)(kh*PADH + kw)*1024u;
    const uint32_t aTap = (uint32_t)tap*1024u;
    for (uint32_t I0b = 0; I0b < 1024; I0b += 128) {   // BK=64 f16
      __syncthreads();
      #pragma unroll
      for (int q = 0; q < 4; ++q) async16(aP[q] + aTap + I0b, aL + q*1024);
      #pragma unroll
      for (int q = 0; q < 4; ++q) async16(bP[q] + bTap + I0b, bL + q*1024);
      __syncthreads();
      #pragma unroll
      for (int ks = 0; ks < 2; ++ks) {
        f16x8 af[4], bf[4];
        #pragma unroll
        for (int i = 0; i < 4; ++i)
          af[i] = As[(wO + i*16 + m)*8 + ((ks*4 + quad) ^ mx)];
        #pragma unroll
        for (int j = 0; j < 4; ++j)
          bf[j] = Bs[(wPq + j*16 + m)*8 + ((ks*4 + quad) ^ mx)];
        #pragma unroll
        for (int i = 0; i < 4; ++i)
          #pragma unroll
          for (int j = 0; j < 4; ++j)
            acc[i][j] = __builtin_amdgcn_mfma_f32_16x16x32_f16(af[i], bf[j], acc[i][j], 0, 0, 0);
      }
    }
  }

  // epilogue: y1[b][O][p] = f16(acc*scale_o + bias); overlap tile double-writes identical values
  #pragma unroll
  for (int i = 0; i < 4; ++i) {
    #pragma unroll
    for (int rr = 0; rr < 4; ++rr) {
      int orow = Ot + wO + i*16 + quad*4 + rr;
      float sc = sco[b*COUT + orow];
      float bb = bias[orow];
      f16* yrow = y1 + ((size_t)(b*COUT + orow))*P_TOT;
      #pragma unroll
      for (int j = 0; j < 4; ++j) {
        int p = pt0 + wPq + j*16 + m;
        yrow[p] = (f16)(acc[i][j][rr]*sc + bb);
      }
    }
  }
}

// ---------------------------------------------------------------- K7: fused up-FIR -> lrelu/clamp -> down-FIR per channel
// v3c: v3b structure (f16 Ylh), pitches trimmed to fit 32KB:
//   YPITCH 76->74, QPITCH 142->138, HPITCH 68->64  => LDS 33904 -> ~32720 B
//   => 5 blocks/CU (20 waves/CU, +25% over v3b) on an occupancy-bound kernel.
// Conflict audit: P3a 4-way read pattern preserved (row residues mod 8 =
// {0,2,4,6} at pitch 138, all distinct); Hr b128 writes / consecutive reads
// are pitch-insensitive. Math byte-identical to v3b.
#define YPITCH 74
#define QPITCH 138
#define HPITCH 64
__global__ __launch_bounds__(256) void k_fir(const f16* __restrict__ y1,
                                             float* __restrict__ out,
                                             FirParams fp) {
  __shared__ __align__(16) f16 Ylh[74*YPITCH];   // padded Y rows/cols -4..69 (10952 B)
  __shared__ __align__(16) float VU[16*YPITCH];  // vertical-up chunk (4736 B)
  __shared__ __align__(16) float Qs[16*QPITCH];  // activated mid rows (8832 B)
  __shared__ __align__(16) float Hr[32*HPITCH];  // rolling horizontal-down rows (8192 B)
  const int tid = threadIdx.x;
  const f16* Y = y1 + (size_t)blockIdx.x * P_TOT;
  float* O = out + (size_t)blockIdx.x * (OUTS*OUTS);

  // stage Y into padded LDS (zero halo via float2, then pure f16x2 copy)
  for (int i = tid; i < 74*YPITCH*2/8; i += 256)   // 1369 float2 = 10952 B exactly
    ((float2*)Ylh)[i] = make_float2(0.f, 0.f);
  __syncthreads();
  const f16x2* Y2 = (const f16x2*)Y;
  for (int i = tid; i < 66*33; i += 256) {
    int r = i/33, d = i - 33*r;
    *(f16x2*)&Ylh[(r+4)*YPITCH + 4 + 2*d] = Y2[33*r + d];
  }
  __syncthreads();

  for (int k = 0; k < 9; ++k) {
    const int m0 = 16*k;
    const int nr = (k < 8) ? 16 : 10;
    const int npair = nr >> 1;

    // ---- P1: vertical polyphase up (pairs share 6 source rows) ----
    for (int it = tid; it < npair*37; it += 256) {
      int p = it/37, c2 = it - 37*p;
      int T = 8*k + p;                 // mid rows 2T,2T+1
      float e0=0.f,e1=0.f,o0=0.f,o1=0.f;
      #pragma unroll
      for (int a = 0; a < 6; ++a) {
        f16x2 hv = *(const f16x2*)&Ylh[(T+5-a)*YPITCH + 2*c2];
        float vx = (float)hv.x, vy = (float)hv.y;
        e0 += fp.fu[2*a]*vx;   e1 += fp.fu[2*a]*vy;
        o0 += fp.fu[2*a+1]*vx; o1 += fp.fu[2*a+1]*vy;
      }
      *(float2*)&VU[(2*p)*YPITCH   + 2*c2] = make_float2(e0, e1);
      *(float2*)&VU[(2*p+1)*YPITCH + 2*c2] = make_float2(o0, o1);
    }
    __syncthreads();

    // ---- P2: horizontal polyphase up + act (3 col-pairs/item, 8 shared reads) ----
    for (int it = tid; it < nr*23; it += 256) {
      int lr = it/23, ug = it - 23*lr;
      int U0 = 3*ug;
      float rv[8];
      #pragma unroll
      for (int d = 0; d < 8; ++d) rv[d] = VU[lr*YPITCH + U0 + d];
      #pragma unroll
      for (int u = 0; u < 3; ++u) {
        float e=0.f, o=0.f;
        #pragma unroll
        for (int t = 0; t < 6; ++t) {
          float v = rv[u+5-t];
          e += fp.fu[2*t]*v; o += fp.fu[2*t+1]*v;
        }
        e = (e >= 0.f ? e : 0.2f*e)*1.4142135623730951f;
        o = (o >= 0.f ? o : 0.2f*o)*1.4142135623730951f;
        e = fminf(fmaxf(e, -256.f), 256.f);
        o = fminf(fmaxf(o, -256.f), 256.f);
        *(float2*)&Qs[lr*QPITCH + 2*(U0+u)] = make_float2(e, o);
      }
    }
    __syncthreads();

    // ---- P3a: horizontal down (exact 256-thread fit at nr=16) ----
    if (tid < nr*16) {
      int lr = tid >> 4, tg = tid & 15;
      float q[18];
      #pragma unroll
      for (int d = 0; d < 18; ++d) q[d] = Qs[lr*QPITCH + 8*tg + d];
      float a0=0.f,a1=0.f,a2=0.f,a3=0.f;
      #pragma unroll
      for (int j = 0; j < 12; ++j) {
        float c = fp.fd[j];
        a0 += c*q[11-j]; a1 += c*q[13-j]; a2 += c*q[15-j]; a3 += c*q[17-j];
      }
      *(float4*)&Hr[((m0+lr)&31)*HPITCH + 4*tg] = make_float4(a0,a1,a2,a3);
    }
    __syncthreads();

    // ---- P3b: vertical down emit, lag 1 chunk (rows 8(k-1)..8k-1) ----
    if (k >= 1) {
      #pragma unroll
      for (int h = 0; h < 2; ++h) {
        int s = tid + 256*h;
        int tr = 8*(k-1) + (s >> 6), tc = s & 63;
        float acc = 0.f;
        #pragma unroll
        for (int j = 0; j < 12; ++j)
          acc += fp.fd[j]*Hr[((2*tr + 11 - j)&31)*HPITCH + tc];
        O[tr*64 + tc] = acc;
      }
    }
    __syncthreads();   // separates P3b reads from next chunk's P3a writes (slot aliasing)
  }
}

// ---------------------------------------------------------------- host: Kaiser lowpass design (double precision)
static double bessel_i0(double x) {
  double t = 0.25*x*x, sum = 1.0, term = 1.0;
  for (int k = 1; k < 64; ++k) {
    term *= t/((double)k*(double)k);
    sum += term;
    if (term < 1e-18*sum) break;
  }
  return sum;
}

static void design_lp(int numtaps, double cutoff, double width, double fs, float* out) {
  const double PI = 3.14159265358979323846;
  double a = 2.285*(numtaps - 1)*PI*(width/(0.5*fs)) + 7.95;
  double beta;
  if (a > 50.0)      beta = 0.1102*(a - 8.7);
  else if (a > 21.0) beta = 0.5842*pow(a - 21.0, 0.4) + 0.07886*(a - 21.0);
  else               beta = 0.0;
  double c = cutoff/(fs*0.5);
  double alpha = (numtaps - 1)*0.5;
  double i0b = bessel_i0(beta);
  double h[16], s = 0.0;
  for (int n = 0; n < numtaps; ++n) {
    double mm = n - alpha;
    double x = c*mm;
    double snc = (x == 0.0) ? 1.0 : sin(PI*x)/(PI*x);
    double r = mm/alpha;
    double kais = bessel_i0(beta*sqrt(fmax(0.0, 1.0 - r*r)))/i0b;
    h[n] = c*snc*kais; s += h[n];
  }
  for (int n = 0; n < numtaps; ++n) out[n] = (float)(h[n]/s);
}

// ---------------------------------------------------------------- launcher
extern "C" void kernel_launch(void* const* d_in, const int* in_sizes, int n_in,
                              void* d_out, int out_size, void* d_ws, size_t ws_size,
                              hipStream_t stream) {
  const float* x  = (const float*)d_in[0];
  const float* w  = (const float*)d_in[1];
  const float* aw = (const float*)d_in[2];
  const float* ab = (const float*)d_in[3];
  const float* cw = (const float*)d_in[4];
  const float* cb = (const float*)d_in[5];
  float* out = (float*)d_out;

  char* ws = (char*)d_ws;
  size_t off = 0;
  auto alloc = [&](size_t bytes) -> char* {
    char* p = ws + off;
    off = (off + bytes + 255) & ~(size_t)255;
    return p;
  };
  float* styles = (float*)alloc(4096*4);
  float* g      = (float*)alloc((size_t)512*512*4);
  float* sco    = (float*)alloc(4096*4);
  f16*   Wp     = (f16*)alloc((size_t)512*9*512*2);
  f16*   Xm     = (f16*)alloc((size_t)BATCH*PADH*PADH*512*2);
  f16*   y1     = (f16*)alloc((size_t)BATCH*COUT*P_TOT*2);
  float* sumsq  = (float*)alloc(4);
  (void)in_sizes; (void)n_in; (void)out_size; (void)ws_size;

  FirParams fp;
  design_lp(12, 32.0, 32.0, 128.0, fp.fu);
  design_lp(12, 32.0, 32.0, 128.0, fp.fd);
  for (int i = 0; i < 12; ++i) fp.fu[i] *= 2.0f;   // x2 per up stage = x4 total up gain (exact)

  hipMemsetAsync(sumsq, 0, 4, stream);
  hipLaunchKernelGGL(k_prep, dim3(1536), dim3(256), 0, stream, cw, Wp, g, w, aw, ab, styles, sumsq);
  hipLaunchKernelGGL(k_xm,   dim3(4128), dim3(256), 0, stream, x, styles, sumsq, Xm, g, sco);
  hipLaunchKernelGGL(k_conv, dim3(1120), dim3(256), 0, stream, Wp, Xm, sco, cb, y1);
  hipLaunchKernelGGL(k_fir,  dim3(4096), dim3(256), 0, stream, y1, out, fp);
}

// Round 9
// 439.340 us; speedup vs baseline: 1.0295x; 1.0295x over previous
//
#include <hip/hip_runtime.h>
#include <cmath>
#include <cstdint>
#include <cstddef>

typedef _Float16 f16;
typedef _Float16 f16x2 __attribute__((ext_vector_type(2)));
typedef _Float16 f16x8 __attribute__((ext_vector_type(8)));
typedef float f32x4 __attribute__((ext_vector_type(4)));

// ---- problem constants ----
#define BATCH 8
#define CIN   512
#define COUT  512
#define S0    64      // input spatial
#define S1    66      // conv output spatial (pad 2, k=3)
#define PADH  68      // padded input spatial for conv
#define P_TOT (S1*S1) // 4356 spatial positions per image
#define MID   138     // mid (upsampled+filtered) spatial
#define OUTS  64      // final output spatial

struct FirParams { float fu[12]; float fd[12]; };

// ---------------------------------------------------------------- helpers
__device__ __forceinline__ void async16(const char* g, char* l) {
  __builtin_amdgcn_global_load_lds((const __attribute__((address_space(1))) void*)g,
                                   (__attribute__((address_space(3))) void*)l, 16, 0, 0);
}

// ---------------------------------------------------------------- K1: fused k_wg + k_styles (independent preps, one launch)
// blocks 0..511: wg role (weight repack + per-O sumsq g)
// blocks 512..1535: styles role (w @ aw^T + ab, global sumsq atomic)
__global__ __launch_bounds__(256) void k_prep(const float* __restrict__ cw,
                                              f16* __restrict__ Wp,
                                              float* __restrict__ g,
                                              const float* __restrict__ w,
                                              const float* __restrict__ aw,
                                              const float* __restrict__ ab,
                                              float* __restrict__ styles,
                                              float* __restrict__ sumsq) {
  __shared__ float part[4];
  if (blockIdx.x < 512) {            // ---- wg role ----
    int O = blockIdx.x;
    const float* base = cw + (size_t)O*4608;
    for (int I = threadIdx.x; I < 512; I += 256) {
      float v[9]; float s = 0.f;
      #pragma unroll
      for (int t = 0; t < 9; ++t) { v[t] = base[I*9 + t]; s += v[t]*v[t]; }
      g[(size_t)O*512 + I] = s;
      #pragma unroll
      for (int t = 0; t < 9; ++t) Wp[((size_t)O*9 + t)*512 + I] = (f16)v[t];
    }
    return;
  }
  // ---- styles role ----
  int wave = threadIdx.x >> 6, lane = threadIdx.x & 63;
  int gid = (blockIdx.x - 512)*4 + wave;         // 0..4095
  int b = gid >> 9, i = gid & 511;
  const float* wr = w + b*512;
  const float* ar = aw + (size_t)i*512;
  float acc = 0.f;
  #pragma unroll
  for (int k = 0; k < 8; ++k) acc += wr[lane + 64*k]*ar[lane + 64*k];
  for (int off = 32; off; off >>= 1) acc += __shfl_down(acc, off);
  if (lane == 0) {
    float v = acc*0.044194173824159216f + ab[i];  // 1/sqrt(512)
    styles[gid] = v;
    part[wave] = v*v;
  }
  __syncthreads();
  if (threadIdx.x == 0) atomicAdd(sumsq, part[0]+part[1]+part[2]+part[3]);
}

// ---------------------------------------------------------------- K4: fused k_xmod + k_halo + k_scale (one launch)
// blocks < 2048:        Xm[b][ih+2][iw+2][I] = f16(x*styles*scale), interior.
//                       float4 reads (16B/lane) + f16x8 stores (16B/lane).
// blocks 2048..3103:    zero Xm halo strips.
// blocks 3104..4127:    scale role: one (b,O) per wave, shfl reduce.
__global__ __launch_bounds__(256) void k_xm(const float* __restrict__ x,
                                            const float* __restrict__ styles,
                                            const float* __restrict__ sumsq,
                                            f16* __restrict__ Xm,
                                            const float* __restrict__ g,
                                            float* __restrict__ sco) {
  __shared__ float tile[128][65];
  if (blockIdx.x >= 3104) {          // ---- scale role ----
    int wave = threadIdx.x >> 6, lane = threadIdx.x & 63;
    int blk2 = (blockIdx.x - 3104)*4 + wave;      // 0..4095 = b*512 + O
    int b = blk2 >> 9, O = blk2 & 511;
    const float* gr = g + (size_t)O*512;
    const float* sr = styles + b*512;
    float a1 = 0.f, a2 = 0.f;
    for (int I = lane; I < 512; I += 64) {
      float gg = gr[I], ss = sr[I];
      a1 += gg*ss*ss; a2 += gg;
    }
    for (int off = 32; off; off >>= 1) {
      a1 += __shfl_down(a1, off);
      a2 += __shfl_down(a2, off);
    }
    if (lane == 0) {
      float kf = 4096.0f / (*sumsq);              // rsqrt(mean styles^2)^2
      a1 *= kf;
      float wn2 = 4608.f / a2;                    // 1/mean(wgt^2)
      sco[blk2] = sqrtf(wn2) / sqrtf(wn2*a1 + 1e-8f);
    }
    return;
  }
  if (blockIdx.x >= 2048) {          // ---- halo role ----
    int pix = (blockIdx.x - 2048)*4 + (threadIdx.x >> 6);   // 0..4223
    int lane = threadIdx.x & 63;
    int img = pix / 528, t = pix - img*528;
    int row, col;
    if (t < 272) { int rid = t/68; col = t - rid*68; row = (rid < 2) ? rid : 64 + rid; }
    else { int t2 = t - 272; int rid = t2 >> 2, cid = t2 & 3; row = rid + 2; col = (cid < 2) ? cid : 64 + cid; }
    float4* p = (float4*)(Xm + ((size_t)(img*PADH + row)*PADH + col)*512);
    p[lane] = make_float4(0.f, 0.f, 0.f, 0.f);
    return;
  }
  int blk = blockIdx.x;              // b*256 + ih*4 + ic
  int ic = blk & 3, ih = (blk >> 2) & 63, b = blk >> 8;
  int I0 = ic*128;
  float sc = sqrtf(4096.0f / (*sumsq));
  const float* xp = x + (((size_t)b*512 + I0)*64 + ih)*64;
  for (int idx = threadIdx.x; idx < 128*16; idx += 256) {
    int Il = idx >> 4, iw4 = (idx & 15) << 2;
    float4 v = *(const float4*)&xp[(size_t)Il*4096 + iw4];
    float s = styles[b*512 + I0 + Il]*sc;
    tile[Il][iw4+0] = v.x*s;
    tile[Il][iw4+1] = v.y*s;
    tile[Il][iw4+2] = v.z*s;
    tile[Il][iw4+3] = v.w*s;
  }
  __syncthreads();
  f16* op = Xm + (((size_t)b*PADH + ih + 2)*PADH + 2)*512 + I0;
  for (int idx = threadIdx.x; idx < 64*16; idx += 256) {
    int iw = idx >> 4, Il0 = (idx & 15) << 3;
    f16x8 vv;
    #pragma unroll
    for (int k = 0; k < 8; ++k) vv[k] = (f16)tile[Il0 + k][iw];
    *(f16x8*)(op + (size_t)iw*512 + Il0) = vv;
  }
}

// ---------------------------------------------------------------- K6: modulated conv as 9-tap implicit GEMM
// 128 O x 128 p tiles, grid 1120 (4.4 blocks/CU for latency hiding).
// b = gid&7 pins image to XCD; within XCD pt fastest + boustrophedon for L2.
// 35 pt-tiles; last overlaps (4228..4355) -> guard-free duplicate stores.
// (explicit dbuf reverted: cut occupancy, -25% — cross-block wave overlap
//  at 32KB LDS IS the pipeline; keep 2-barrier structure.)
// At ~910 TF this sits at the m97-structure ceiling.
__global__ __launch_bounds__(256) void k_conv(const f16* __restrict__ Wp,
                                              const f16* __restrict__ Xm,
                                              const float* __restrict__ sco,
                                              const float* __restrict__ bias,
                                              f16* __restrict__ y1) {
  __shared__ f16x8 As[1024];   // 128 rows x 128B (16KB)
  __shared__ f16x8 Bs[1024];
  const int tid = threadIdx.x, lane = tid & 63, wave = tid >> 6;
  const int gid = blockIdx.x;
  const int b = gid & 7;
  const int r = gid >> 3;            // 0..139
  const int Oi = r / 35;
  int pi = r - Oi*35;                // 0..34
  if (Oi & 1) pi = 34 - pi;          // boustrophedon
  const int Ot = Oi * 128;
  const int pt0 = (pi < 34) ? pi*128 : 4228;

  const int srow = wave*32 + (lane >> 3);
  const int cglob = (lane & 7) ^ (lane >> 3);     // global chunk feeding physical chunk lane&7
  const char* aP[4]; const char* bP[4];
  #pragma unroll
  for (int q = 0; q < 4; ++q) {
    aP[q] = (const char*)Wp + (size_t)(Ot + srow + q*8)*9216 + cglob*16;
    int p = pt0 + srow + q*8;                      // always <= 4355
    int oh = p/66, ow = p - oh*66;
    bP[q] = (const char*)Xm + (((size_t)b*PADH + oh)*PADH + ow)*1024 + cglob*16;
  }
  char* aL = (char*)As + wave*32*128;
  char* bL = (char*)Bs + wave*32*128;

  f32x4 acc[4][4] = {};
  const int wO = (wave & 1)*64, wPq = (wave >> 1)*64;
  const int m = lane & 15, quad = lane >> 4, mx = m & 7;

  for (int tap = 0; tap < 9; ++tap) {
    const int kh = tap/3, kw = tap - kh*3;
    const uint32_t bTap = (uint32_t)(kh*PADH + kw)*1024u;
    const uint32_t aTap = (uint32_t)tap*1024u;
    for (uint32_t I0b = 0; I0b < 1024; I0b += 128) {   // BK=64 f16
      __syncthreads();
      #pragma unroll
      for (int q = 0; q < 4; ++q) async16(aP[q] + aTap + I0b, aL + q*1024);
      #pragma unroll
      for (int q = 0; q < 4; ++q) async16(bP[q] + bTap + I0b, bL + q*1024);
      __syncthreads();
      #pragma unroll
      for (int ks = 0; ks < 2; ++ks) {
        f16x8 af[4], bf[4];
        #pragma unroll
        for (int i = 0; i < 4; ++i)
          af[i] = As[(wO + i*16 + m)*8 + ((ks*4 + quad) ^ mx)];
        #pragma unroll
        for (int j = 0; j < 4; ++j)
          bf[j] = Bs[(wPq + j*16 + m)*8 + ((ks*4 + quad) ^ mx)];
        #pragma unroll
        for (int i = 0; i < 4; ++i)
          #pragma unroll
          for (int j = 0; j < 4; ++j)
            acc[i][j] = __builtin_amdgcn_mfma_f32_16x16x32_f16(af[i], bf[j], acc[i][j], 0, 0, 0);
      }
    }
  }

  // epilogue: y1[b][O][p] = f16(acc*scale_o + bias); overlap tile double-writes identical values
  #pragma unroll
  for (int i = 0; i < 4; ++i) {
    #pragma unroll
    for (int rr = 0; rr < 4; ++rr) {
      int orow = Ot + wO + i*16 + quad*4 + rr;
      float sc = sco[b*COUT + orow];
      float bb = bias[orow];
      f16* yrow = y1 + ((size_t)(b*COUT + orow))*P_TOT;
      #pragma unroll
      for (int j = 0; j < 4; ++j) {
        int p = pt0 + wPq + j*16 + m;
        yrow[p] = (f16)(acc[i][j][rr]*sc + bb);
      }
    }
  }
}

// ---------------------------------------------------------------- K7: fused up-FIR -> lrelu/clamp -> down-FIR per channel
// v4 (DS-throughput attack): r8 showed 4->5 blocks/CU is a NULL => fir is
// bound by per-CU DS instruction throughput, not occupancy. So cut DS ops:
//  - P3a: QPITCH 138->140 (row stride % 16B == 0) so q[18] loads become
//    4x ds_read_b128 + 1x b64 (was 18 scalar b32, 4-way bank-conflicted).
//  - P3b: each thread emits out rows (tr, tr+4) together; their H windows
//    share 4 rows -> 20 reads / 2 outputs (was 24). Max H row at k=8 is
//    2*(8k-5)+19 = 137 (exists); 32-slot circular window unchanged.
// Accumulation order identical => bit-identical results. LDS 32848 B
// (4 blocks/CU — proven neutral in r8).
#define YPITCH 74
#define QPITCH 140
#define HPITCH 64
__global__ __launch_bounds__(256) void k_fir(const f16* __restrict__ y1,
                                             float* __restrict__ out,
                                             FirParams fp) {
  __shared__ __align__(16) f16 Ylh[74*YPITCH];   // padded Y rows/cols -4..69 (10952 B)
  __shared__ __align__(16) float VU[16*YPITCH];  // vertical-up chunk (4736 B)
  __shared__ __align__(16) float Qs[16*QPITCH];  // activated mid rows (8960 B)
  __shared__ __align__(16) float Hr[32*HPITCH];  // rolling horizontal-down rows (8192 B)
  const int tid = threadIdx.x;
  const f16* Y = y1 + (size_t)blockIdx.x * P_TOT;
  float* O = out + (size_t)blockIdx.x * (OUTS*OUTS);

  // stage Y into padded LDS (zero halo via float2, then pure f16x2 copy)
  for (int i = tid; i < 74*YPITCH*2/8; i += 256)   // 1369 float2 = 10952 B exactly
    ((float2*)Ylh)[i] = make_float2(0.f, 0.f);
  __syncthreads();
  const f16x2* Y2 = (const f16x2*)Y;
  for (int i = tid; i < 66*33; i += 256) {
    int r = i/33, d = i - 33*r;
    *(f16x2*)&Ylh[(r+4)*YPITCH + 4 + 2*d] = Y2[33*r + d];
  }
  __syncthreads();

  for (int k = 0; k < 9; ++k) {
    const int m0 = 16*k;
    const int nr = (k < 8) ? 16 : 10;
    const int npair = nr >> 1;

    // ---- P1: vertical polyphase up (pairs share 6 source rows) ----
    for (int it = tid; it < npair*37; it += 256) {
      int p = it/37, c2 = it - 37*p;
      int T = 8*k + p;                 // mid rows 2T,2T+1
      float e0=0.f,e1=0.f,o0=0.f,o1=0.f;
      #pragma unroll
      for (int a = 0; a < 6; ++a) {
        f16x2 hv = *(const f16x2*)&Ylh[(T+5-a)*YPITCH + 2*c2];
        float vx = (float)hv.x, vy = (float)hv.y;
        e0 += fp.fu[2*a]*vx;   e1 += fp.fu[2*a]*vy;
        o0 += fp.fu[2*a+1]*vx; o1 += fp.fu[2*a+1]*vy;
      }
      *(float2*)&VU[(2*p)*YPITCH   + 2*c2] = make_float2(e0, e1);
      *(float2*)&VU[(2*p+1)*YPITCH + 2*c2] = make_float2(o0, o1);
    }
    __syncthreads();

    // ---- P2: horizontal polyphase up + act (3 col-pairs/item, 8 shared reads) ----
    for (int it = tid; it < nr*23; it += 256) {
      int lr = it/23, ug = it - 23*lr;
      int U0 = 3*ug;
      float rv[8];
      #pragma unroll
      for (int d = 0; d < 8; ++d) rv[d] = VU[lr*YPITCH + U0 + d];
      #pragma unroll
      for (int u = 0; u < 3; ++u) {
        float e=0.f, o=0.f;
        #pragma unroll
        for (int t = 0; t < 6; ++t) {
          float v = rv[u+5-t];
          e += fp.fu[2*t]*v; o += fp.fu[2*t+1]*v;
        }
        e = (e >= 0.f ? e : 0.2f*e)*1.4142135623730951f;
        o = (o >= 0.f ? o : 0.2f*o)*1.4142135623730951f;
        e = fminf(fmaxf(e, -256.f), 256.f);
        o = fminf(fmaxf(o, -256.f), 256.f);
        *(float2*)&Qs[lr*QPITCH + 2*(U0+u)] = make_float2(e, o);
      }
    }
    __syncthreads();

    // ---- P3a: horizontal down (vectorized b128 reads; exact 256-thread fit) ----
    if (tid < nr*16) {
      int lr = tid >> 4, tg = tid & 15;
      const float* qb = &Qs[lr*QPITCH + 8*tg];    // 16B-aligned (QPITCH%4==0, 8*tg%4==0)
      float4 v0 = *(const float4*)(qb + 0);
      float4 v1 = *(const float4*)(qb + 4);
      float4 v2 = *(const float4*)(qb + 8);
      float4 v3 = *(const float4*)(qb + 12);
      float2 v4 = *(const float2*)(qb + 16);
      float q[18] = { v0.x,v0.y,v0.z,v0.w, v1.x,v1.y,v1.z,v1.w,
                      v2.x,v2.y,v2.z,v2.w, v3.x,v3.y,v3.z,v3.w, v4.x,v4.y };
      float a0=0.f,a1=0.f,a2=0.f,a3=0.f;
      #pragma unroll
      for (int j = 0; j < 12; ++j) {
        float c = fp.fd[j];
        a0 += c*q[11-j]; a1 += c*q[13-j]; a2 += c*q[15-j]; a3 += c*q[17-j];
      }
      *(float4*)&Hr[((m0+lr)&31)*HPITCH + 4*tg] = make_float4(a0,a1,a2,a3);
    }
    __syncthreads();

    // ---- P3b: vertical down emit, lag 1 chunk; rows (tr, tr+4) share 4 H rows ----
    if (k >= 1) {
      int tr = 8*(k-1) + (tid >> 6);   // tid>>6 in 0..3; pair rows tr, tr+4
      int tc = tid & 63;
      float hv[20];
      #pragma unroll
      for (int e = 0; e < 20; ++e)
        hv[e] = Hr[((2*tr + e)&31)*HPITCH + tc];
      float acc0 = 0.f, acc1 = 0.f;
      #pragma unroll
      for (int j = 0; j < 12; ++j) {
        acc0 += fp.fd[j]*hv[11-j];     // out row tr:   H[2tr+11-j]
        acc1 += fp.fd[j]*hv[19-j];     // out row tr+4: H[2(tr+4)+11-j]
      }
      O[tr*64 + tc]     = acc0;
      O[(tr+4)*64 + tc] = acc1;
    }
    __syncthreads();   // separates P3b reads from next chunk's P3a writes (slot aliasing)
  }
}

// ---------------------------------------------------------------- host: Kaiser lowpass design (double precision)
static double bessel_i0(double x) {
  double t = 0.25*x*x, sum = 1.0, term = 1.0;
  for (int k = 1; k < 64; ++k) {
    term *= t/((double)k*(double)k);
    sum += term;
    if (term < 1e-18*sum) break;
  }
  return sum;
}

static void design_lp(int numtaps, double cutoff, double width, double fs, float* out) {
  const double PI = 3.14159265358979323846;
  double a = 2.285*(numtaps - 1)*PI*(width/(0.5*fs)) + 7.95;
  double beta;
  if (a > 50.0)      beta = 0.1102*(a - 8.7);
  else if (a > 21.0) beta = 0.5842*pow(a - 21.0, 0.4) + 0.07886*(a - 21.0);
  else               beta = 0.0;
  double c = cutoff/(fs*0.5);
  double alpha = (numtaps - 1)*0.5;
  double i0b = bessel_i0(beta);
  double h[16], s = 0.0;
  for (int n = 0; n < numtaps; ++n) {
    double mm = n - alpha;
    double x = c*mm;
    double snc = (x == 0.0) ? 1.0 : sin(PI*x)/(PI*x);
    double r = mm/alpha;
    double kais = bessel_i0(beta*sqrt(fmax(0.0, 1.0 - r*r)))/i0b;
    h[n] = c*snc*kais; s += h[n];
  }
  for (int n = 0; n < numtaps; ++n) out[n] = (float)(h[n]/s);
}

// ---------------------------------------------------------------- launcher
extern "C" void kernel_launch(void* const* d_in, const int* in_sizes, int n_in,
                              void* d_out, int out_size, void* d_ws, size_t ws_size,
                              hipStream_t stream) {
  const float* x  = (const float*)d_in[0];
  const float* w  = (const float*)d_in[1];
  const float* aw = (const float*)d_in[2];
  const float* ab = (const float*)d_in[3];
  const float* cw = (const float*)d_in[4];
  const float* cb = (const float*)d_in[5];
  float* out = (float*)d_out;

  char* ws = (char*)d_ws;
  size_t off = 0;
  auto alloc = [&](size_t bytes) -> char* {
    char* p = ws + off;
    off = (off + bytes + 255) & ~(size_t)255;
    return p;
  };
  float* styles = (float*)alloc(4096*4);
  float* g      = (float*)alloc((size_t)512*512*4);
  float* sco    = (float*)alloc(4096*4);
  f16*   Wp     = (f16*)alloc((size_t)512*9*512*2);
  f16*   Xm     = (f16*)alloc((size_t)BATCH*PADH*PADH*512*2);
  f16*   y1     = (f16*)alloc((size_t)BATCH*COUT*P_TOT*2);
  float* sumsq  = (float*)alloc(4);
  (void)in_sizes; (void)n_in; (void)out_size; (void)ws_size;

  FirParams fp;
  design_lp(12, 32.0, 32.0, 128.0, fp.fu);
  design_lp(12, 32.0, 32.0, 128.0, fp.fd);
  for (int i = 0; i < 12; ++i) fp.fu[i] *= 2.0f;   // x2 per up stage = x4 total up gain (exact)

  hipMemsetAsync(sumsq, 0, 4, stream);
  hipLaunchKernelGGL(k_prep, dim3(1536), dim3(256), 0, stream, cw, Wp, g, w, aw, ab, styles, sumsq);
  hipLaunchKernelGGL(k_xm,   dim3(4128), dim3(256), 0, stream, x, styles, sumsq, Xm, g, sco);
  hipLaunchKernelGGL(k_conv, dim3(1120), dim3(256), 0, stream, Wp, Xm, sco, cb, y1);
  hipLaunchKernelGGL(k_fir,  dim3(4096), dim3(256), 0, stream, y1, out, fp);
}